// Round 1
// baseline (669.651 us; speedup 1.0000x reference)
//
#include <hip/hip_runtime.h>

#define NSEG 256
#define D 128
#define COL4 (D / 4)   // 32 float4 per row

// ws layout: int starts[NSEG+1]
__global__ void init_starts_kernel(int* starts, int n) {
    int i = blockIdx.x * blockDim.x + threadIdx.x;
    if (i <= NSEG) starts[i] = n;
}

__global__ void find_starts_kernel(const int* __restrict__ seg, int n, int* __restrict__ starts) {
    int i = blockIdx.x * blockDim.x + threadIdx.x;
    if (i < n) {
        int s = seg[i];
        if (i == 0 || seg[i - 1] != s) starts[s] = i;
    }
}

// One block per segment. 1024 threads: col = tid&31 (float4 column), slot = tid>>5 (row slot).
__global__ __launch_bounds__(1024) void seg_mean_kernel(const float4* __restrict__ inp,
                                                        const int* __restrict__ starts,
                                                        float* __restrict__ out, int n) {
    const int s = blockIdx.x;
    __shared__ int sh_bounds[2];
    if (threadIdx.x == 0) {
        int st = starts[s];
        int en = n;
        // next valid start (all segments present by construction -> exits on first probe)
        for (int t = s + 1; t <= NSEG; ++t) {
            int v = starts[t];
            if (v < n) { en = v; break; }
        }
        sh_bounds[0] = st;
        sh_bounds[1] = en;
    }
    __syncthreads();
    const int start = sh_bounds[0];
    const int end   = sh_bounds[1];

    const int col  = threadIdx.x & (COL4 - 1);
    const int slot = threadIdx.x >> 5;

    float4 acc = make_float4(0.f, 0.f, 0.f, 0.f);
    // stream rows start+slot, start+slot+32, ... ; coalesced float4 loads
    #pragma unroll 4
    for (int r = start + slot; r < end; r += 32) {
        float4 v = inp[(size_t)r * COL4 + col];
        acc.x += v.x; acc.y += v.y; acc.z += v.z; acc.w += v.w;
    }

    // 32-slot tree reduction in LDS
    __shared__ float4 red[32][COL4];  // 16 KiB
    red[slot][col] = acc;
    __syncthreads();
    #pragma unroll
    for (int stride = 16; stride >= 1; stride >>= 1) {
        if (slot < stride) {
            float4 a = red[slot][col];
            float4 b = red[slot + stride][col];
            a.x += b.x; a.y += b.y; a.z += b.z; a.w += b.w;
            red[slot][col] = a;
        }
        __syncthreads();
    }

    if (slot == 0) {
        int cnt = end - start;          // may be <=0 for absent segment -> output 0
        float inv = 1.0f / (float)(cnt > 1 ? cnt : 1);
        float4 a = red[0][col];
        float4 o = make_float4(a.x * inv, a.y * inv, a.z * inv, a.w * inv);
        ((float4*)out)[(size_t)s * COL4 + col] = o;
    }
}

extern "C" void kernel_launch(void* const* d_in, const int* in_sizes, int n_in,
                              void* d_out, int out_size, void* d_ws, size_t ws_size,
                              hipStream_t stream) {
    const float* inp = (const float*)d_in[0];
    const int* seg   = (const int*)d_in[1];
    float* out       = (float*)d_out;
    const int n = in_sizes[1];          // 1048576 rows

    int* starts = (int*)d_ws;           // NSEG+1 ints

    init_starts_kernel<<<2, 256, 0, stream>>>(starts, n);
    find_starts_kernel<<<(n + 255) / 256, 256, 0, stream>>>(seg, n, starts);
    seg_mean_kernel<<<NSEG, 1024, 0, stream>>>((const float4*)inp, starts, out, n);
}